// Round 19
// baseline (22.713 us; speedup 1.0000x reference)
//
#include <hip/hip_runtime.h>

// Problem constants: B=8, N=1024, F=128, H=4, K=32, TAU=1
typedef unsigned int uint32;
typedef unsigned short ushort16;

#define P1_PTS 16      // points per A-block
#define P1_BLOCKS 512  // 8192 / P1_PTS
#define NCHUNK_B 64    // chunks per batch = 1024 / P1_PTS
#define KQS 129        // padded float4 stride per (q,j) key slot (2-way-free)

// round-to-nearest-even f32 -> bf16 bits
static __device__ __forceinline__ ushort16 f2bf(float f) {
  uint32 u = __float_as_uint(f);
  return (ushort16)((u + 0x7FFFu + ((u >> 16) & 1u)) >> 16);
}

// ---------------------------------------------------------------------------
// A: r14 structure + in-block key staging (NO extra dispatch).
// r14's key loads were uncoalesced (lane=key-row -> 512B lane stride, ~64
// L1 lines per load instr -> TA serialization ~3.4us/CU). Here each block
// stages keys into LDS in TWO 32KB passes: coalesced global reads of the
// original [hk][f] layout, transposed write to klds[q][j][hk] (stride 129
// float4 -> staging writes 2-way-free, dist reads lane=hk conflict-free
// b128). The accs quarter-combine buffer ALIASES the key buffer (keys dead
// after dist loop; barrier-separated) -> LDS ~51KB, same 2 blk/CU as r14.
// Downstream math identical to r14 -> bit-identical output.
// ---------------------------------------------------------------------------
__global__ __launch_bounds__(256, 2) void mempool_A(
    const float* __restrict__ x, const float* __restrict__ keys,
    const float* __restrict__ conv_w, float* __restrict__ S_out,
    uint32* __restrict__ part) {
  const int t = threadIdx.x;
  const int hkp = t & 63;
  const int q = t >> 6;  // f-quarter 0..3

  __shared__ float4 klds4[16 * KQS];     // key slots [q][j'][hk], 33 KB
  __shared__ float4 xl[P1_PTS * 32];     // [p][fq], 8 KB
  __shared__ float cwsn[P1_PTS][4][32];  // [p][h][k], 8 KB
  __shared__ float sl[P1_PTS][32];       // [p][k], 2 KB
  float* accs = reinterpret_cast<float*>(klds4);  // alias: [p][q][hk] floats

  const int bn0 = blockIdx.x * P1_PTS;
  const float4* keys4 = reinterpret_cast<const float4*>(keys);

  // Stage x: 512 float4 = 2 per thread, fully coalesced.
  {
    const float4* xg = reinterpret_cast<const float4*>(x) + (size_t)bn0 * 32;
    xl[t] = xg[t];
    xl[t + 256] = xg[t + 256];
  }
  // Stage keys pass 0 (j in [0,4)): 2048 float4, 8 per thread, coalesced
  // 64B segments; transposed write, 2-way-free via KQS=129 padding.
#pragma unroll
  for (int i = 0; i < 8; ++i) {
    const int s = t + i * 256;
    const int hk = s >> 4, r = s & 15, qq = r >> 2, j4 = r & 3;
    klds4[(qq * 4 + j4) * KQS + hk] = keys4[hk * 32 + qq * 8 + j4];
  }
  __syncthreads();

  float acc0[P1_PTS], acc1[P1_PTS];
#pragma unroll
  for (int p = 0; p < P1_PTS; ++p) acc0[p] = acc1[p] = 0.f;

  // Dist pass 0: j in [0,4). Key reads: lane=hkp consecutive -> b128
  // conflict-free. x reads wave-uniform -> broadcast.
#pragma unroll
  for (int j = 0; j < 4; ++j) {
    const float4 kv0 = klds4[(q * 4 + j) * KQS + hkp];
    const float4 kv1 = klds4[(q * 4 + j) * KQS + hkp + 64];
    const int jj = q * 8 + j;
#pragma unroll
    for (int p = 0; p < P1_PTS; ++p) {
      const float4 xv = xl[p * 32 + jj];
      acc0[p] += fabsf(kv0.x - xv.x) + fabsf(kv0.y - xv.y) +
                 fabsf(kv0.z - xv.z) + fabsf(kv0.w - xv.w);
      acc1[p] += fabsf(kv1.x - xv.x) + fabsf(kv1.y - xv.y) +
                 fabsf(kv1.z - xv.z) + fabsf(kv1.w - xv.w);
    }
  }
  __syncthreads();  // pass-0 key reads done before restage

  // Stage keys pass 1 (j in [4,8)).
#pragma unroll
  for (int i = 0; i < 8; ++i) {
    const int s = t + i * 256;
    const int hk = s >> 4, r = s & 15, qq = r >> 2, j4 = r & 3;
    klds4[(qq * 4 + j4) * KQS + hk] = keys4[hk * 32 + qq * 8 + j4 + 4];
  }
  __syncthreads();

  // Dist pass 1: j in [4,8).
#pragma unroll
  for (int j = 4; j < 8; ++j) {
    const float4 kv0 = klds4[(q * 4 + (j - 4)) * KQS + hkp];
    const float4 kv1 = klds4[(q * 4 + (j - 4)) * KQS + hkp + 64];
    const int jj = q * 8 + j;
#pragma unroll
    for (int p = 0; p < P1_PTS; ++p) {
      const float4 xv = xl[p * 32 + jj];
      acc0[p] += fabsf(kv0.x - xv.x) + fabsf(kv0.y - xv.y) +
                 fabsf(kv0.z - xv.z) + fabsf(kv0.w - xv.w);
      acc1[p] += fabsf(kv1.x - xv.x) + fabsf(kv1.y - xv.y) +
                 fabsf(kv1.z - xv.z) + fabsf(kv1.w - xv.w);
    }
  }
  __syncthreads();  // ALL klds reads done -> accs alias safe

  // Quarter partials into (aliased) accs: [p][q][hk] floats, conflict-free.
#pragma unroll
  for (int p = 0; p < P1_PTS; ++p) {
    accs[(p * 4 + q) * 128 + hkp] = acc0[p];
    accs[(p * 4 + q) * 128 + hkp + 64] = acc1[p];
  }
  __syncthreads();

  // Quarter-combine + Student-t + per-head normalize.
  // 2048 (p,hk) cells / 256 threads = 8 each; 32-lane groups share (p,h).
  const float4 cwv = *reinterpret_cast<const float4*>(conv_w);
  {
    const int hk = t & 127;
    const float cw = (hk & 64) ? ((hk & 32) ? cwv.w : cwv.z)
                               : ((hk & 32) ? cwv.y : cwv.x);
#pragma unroll
    for (int i = 0; i < 8; ++i) {
      const int p = (t >> 7) + 2 * i;
      const float d = accs[(p * 4 + 0) * 128 + hk] +
                      accs[(p * 4 + 1) * 128 + hk] +
                      accs[(p * 4 + 2) * 128 + hk] +
                      accs[(p * 4 + 3) * 128 + hk];
      const float tv = __builtin_amdgcn_rcpf(1.f + d * d);  // Student-t, tau=1
      float hs = tv;
#pragma unroll
      for (int m = 1; m < 32; m <<= 1) hs += __shfl_xor(hs, m);
      cwsn[p][hk >> 5][hk & 31] = cw * tv * __builtin_amdgcn_rcpf(hs);
    }
  }
  __syncthreads();

  // Conv-combine over heads + softmax over k. 16 p x 32 k = 2 passes.
#pragma unroll
  for (int pp = 0; pp < 2; ++pp) {
    const int p = pp * 8 + (t >> 5);
    const int k = t & 31;
    float sc = cwsn[p][0][k] + cwsn[p][1][k] + cwsn[p][2][k] + cwsn[p][3][k];
    float mx = sc;
#pragma unroll
    for (int m = 1; m < 32; m <<= 1) mx = fmaxf(mx, __shfl_xor(mx, m));
    const float e = __expf(sc - mx);
    float se = e;
#pragma unroll
    for (int m = 1; m < 32; m <<= 1) se += __shfl_xor(se, m);
    const float sv = e * __builtin_amdgcn_rcpf(se);
    S_out[(size_t)(bn0 + p) * 32 + k] = sv;
    sl[p][k] = sv;
  }
  __syncthreads();

  // Partial pooled (bf16 pairs in uint32), normal cached vector stores.
  {
    const int k = t & 31;
    const int fs = t >> 5;
    float4 a0 = {0, 0, 0, 0}, a1 = {0, 0, 0, 0}, a2 = {0, 0, 0, 0},
           a3 = {0, 0, 0, 0};
#pragma unroll
    for (int p = 0; p < P1_PTS; ++p) {
      const float s = sl[p][k];
      const float4 v0 = xl[p * 32 + fs * 4 + 0];
      const float4 v1 = xl[p * 32 + fs * 4 + 1];
      const float4 v2 = xl[p * 32 + fs * 4 + 2];
      const float4 v3 = xl[p * 32 + fs * 4 + 3];
      a0.x += s * v0.x; a0.y += s * v0.y; a0.z += s * v0.z; a0.w += s * v0.w;
      a1.x += s * v1.x; a1.y += s * v1.y; a1.z += s * v1.z; a1.w += s * v1.w;
      a2.x += s * v2.x; a2.y += s * v2.y; a2.z += s * v2.z; a2.w += s * v2.w;
      a3.x += s * v3.x; a3.y += s * v3.y; a3.z += s * v3.z; a3.w += s * v3.w;
    }
    uint32 w0 = f2bf(a0.x) | ((uint32)f2bf(a0.y) << 16);
    uint32 w1 = f2bf(a0.z) | ((uint32)f2bf(a0.w) << 16);
    uint32 w2 = f2bf(a1.x) | ((uint32)f2bf(a1.y) << 16);
    uint32 w3 = f2bf(a1.z) | ((uint32)f2bf(a1.w) << 16);
    uint32 w4 = f2bf(a2.x) | ((uint32)f2bf(a2.y) << 16);
    uint32 w5 = f2bf(a2.z) | ((uint32)f2bf(a2.w) << 16);
    uint32 w6 = f2bf(a3.x) | ((uint32)f2bf(a3.y) << 16);
    uint32 w7 = f2bf(a3.z) | ((uint32)f2bf(a3.w) << 16);
    uint4* dst = reinterpret_cast<uint4*>(
        part + (((size_t)blockIdx.x * 32 + k) * 64 + fs * 8));
    dst[0] = make_uint4(w0, w1, w2, w3);
    dst[1] = make_uint4(w4, w5, w6, w7);
  }
}

// ---------------------------------------------------------------------------
// Out: block = (b,k), 256 threads (r8/r14-proven).
// ---------------------------------------------------------------------------
__global__ __launch_bounds__(256) void mempool_out(
    const uint32* __restrict__ part, const float* __restrict__ lin_w,
    float* __restrict__ out) {
  const int b = blockIdx.x >> 5;
  const int k = blockIdx.x & 31;
  const int t = threadIdx.x;
  const int f2 = t & 63;
  const int ch = t >> 6;  // 0..3

  __shared__ float red[4][128];
  __shared__ float pooled[128];

  float sx = 0.f, sy = 0.f;
  const uint32* pp =
      part + ((size_t)((b * NCHUNK_B + ch * 16) * 32 + k)) * 64 + f2;
#pragma unroll
  for (int cc = 0; cc < 16; ++cc) {
    const uint32 v = pp[(size_t)cc * 32 * 64];
    sx += __uint_as_float(v << 16);
    sy += __uint_as_float(v & 0xFFFF0000u);
  }
  red[ch][f2 * 2] = sx;
  red[ch][f2 * 2 + 1] = sy;
  __syncthreads();

  if (t < 128) pooled[t] = red[0][t] + red[1][t] + red[2][t] + red[3][t];
  __syncthreads();

  if (t < 128) {
    const float4* w4 = reinterpret_cast<const float4*>(lin_w) + t * 32;
    const float4* pl4 = reinterpret_cast<const float4*>(pooled);
    float o = 0.f;
#pragma unroll
    for (int j = 0; j < 32; ++j) {
      const float4 w = w4[j];
      const float4 p = pl4[j];
      o += w.x * p.x + w.y * p.y + w.z * p.z + w.w * p.w;
    }
    o = (o >= 0.f) ? o : 0.01f * o;
    out[(size_t)(b * 32 + k) * 128 + t] = o;
  }
}

// ---------------------------------------------------------------------------
// Fallbacks (no workspace): round-1 structure (known-good).
// ---------------------------------------------------------------------------
__global__ __launch_bounds__(256) void mempool_phase1_fb(
    const float* __restrict__ x, const float* __restrict__ keys,
    const float* __restrict__ conv_w, float* __restrict__ S_out) {
  const int t = threadIdx.x;
  const int hk = t & 127;
  const int half = t >> 7;

  const float4* kq = reinterpret_cast<const float4*>(keys) + hk * 32 + half * 16;
  const float cw = conv_w[(t >> 5) & 3];

  __shared__ float lds_half[128];
  __shared__ float lds_ws[128];

  const int base = blockIdx.x * 8;
  for (int p = 0; p < 8; ++p) {
    const int bn = base + p;
    const float4* xq = reinterpret_cast<const float4*>(x) + bn * 32 + half * 16;
    float a0 = 0.f;
#pragma unroll
    for (int j = 0; j < 16; ++j) {
      const float4 kv = kq[j];
      const float4 xv = xq[j];
      a0 += fabsf(kv.x - xv.x) + fabsf(kv.y - xv.y) + fabsf(kv.z - xv.z) +
            fabsf(kv.w - xv.w);
    }
    if (t >= 128) lds_half[hk] = a0;
    __syncthreads();
    if (t < 128) {
      const float d = a0 + lds_half[hk];
      const float tv = 1.0f / (1.0f + d * d);
      float hs = tv;
#pragma unroll
      for (int m = 1; m < 32; m <<= 1) hs += __shfl_xor(hs, m);
      lds_ws[hk] = cw * tv / hs;
    }
    __syncthreads();
    if (t < 32) {
      float sc = lds_ws[t] + lds_ws[32 + t] + lds_ws[64 + t] + lds_ws[96 + t];
      float mx = sc;
#pragma unroll
      for (int m = 1; m < 32; m <<= 1) mx = fmaxf(mx, __shfl_xor(mx, m));
      const float e = __expf(sc - mx);
      float se = e;
#pragma unroll
      for (int m = 1; m < 32; m <<= 1) se += __shfl_xor(se, m);
      S_out[bn * 32 + t] = e / se;
    }
    __syncthreads();
  }
}

__global__ __launch_bounds__(256) void mempool_phase2_fb(
    const float* __restrict__ x, const float* __restrict__ S,
    const float* __restrict__ lin_w, float* __restrict__ out) {
  const int b = blockIdx.x >> 5;
  const int k = blockIdx.x & 31;
  const int t = threadIdx.x;
  const int fq = t & 31;
  const int seg = t >> 5;

  const float4* xq = reinterpret_cast<const float4*>(x) + (size_t)b * 1024 * 32;
  const float* Sb = S + (size_t)b * 1024 * 32 + k;

  float4 acc = {0.f, 0.f, 0.f, 0.f};
  const int n0 = seg * 128;
#pragma unroll 4
  for (int n = n0; n < n0 + 128; ++n) {
    const float sv = Sb[(size_t)n * 32];
    const float4 xv = xq[n * 32 + fq];
    acc.x += sv * xv.x;
    acc.y += sv * xv.y;
    acc.z += sv * xv.z;
    acc.w += sv * xv.w;
  }

  __shared__ float4 red[8][32];
  red[seg][fq] = acc;
  __syncthreads();

  __shared__ float4 pooled4[32];
  if (t < 32) {
    float4 a = red[0][t];
#pragma unroll
    for (int ss = 1; ss < 8; ++ss) {
      const float4 r = red[ss][t];
      a.x += r.x; a.y += r.y; a.z += r.z; a.w += r.w;
    }
    pooled4[t] = a;
  }
  __syncthreads();

  if (t < 128) {
    const float4* wq = reinterpret_cast<const float4*>(lin_w) + t * 32;
    float o = 0.f;
#pragma unroll
    for (int j = 0; j < 32; ++j) {
      const float4 w = wq[j];
      const float4 p = pooled4[j];
      o += w.x * p.x + w.y * p.y + w.z * p.z + w.w * p.w;
    }
    o = (o >= 0.f) ? o : 0.01f * o;
    out[(size_t)(b * 32 + k) * 128 + t] = o;
  }
}

extern "C" void kernel_launch(void* const* d_in, const int* in_sizes, int n_in,
                              void* d_out, int out_size, void* d_ws, size_t ws_size,
                              hipStream_t stream) {
  const float* x = (const float*)d_in[0];       // [8,1024,128]
  const float* keys = (const float*)d_in[1];    // [4,32,128]
  const float* conv_w = (const float*)d_in[2];  // [4]
  const float* lin_w = (const float*)d_in[3];   // [128,128]

  float* out = (float*)d_out;            // [8,32,128]
  float* S_out = (float*)d_out + 32768;  // [8,1024,32]

  const size_t part_bytes = (size_t)P1_BLOCKS * 32 * 128 * 2;  // 4 MB bf16

  if (ws_size >= part_bytes) {
    uint32* part = (uint32*)d_ws;
    mempool_A<<<P1_BLOCKS, 256, 0, stream>>>(x, keys, conv_w, S_out, part);
    mempool_out<<<8 * 32, 256, 0, stream>>>(part, lin_w, out);
  } else {
    mempool_phase1_fb<<<1024, 256, 0, stream>>>(x, keys, conv_w, S_out);
    mempool_phase2_fb<<<8 * 32, 256, 0, stream>>>(x, S_out, lin_w, out);
  }
}

// Round 20
// 22.461 us; speedup vs baseline: 1.0112x; 1.0112x over previous
//
#include <hip/hip_runtime.h>

// Problem constants: B=8, N=1024, F=128, H=4, K=32, TAU=1
typedef unsigned int uint32;
typedef unsigned short ushort16;

#define P1_PTS 16      // points per A-block
#define P1_BLOCKS 512  // 8192 / P1_PTS
#define NCHUNK_B 64    // chunks per batch = 1024 / P1_PTS

// round-to-nearest-even f32 -> bf16 bits
static __device__ __forceinline__ ushort16 f2bf(float f) {
  uint32 u = __float_as_uint(f);
  return (ushort16)((u + 0x7FFFu + ((u >> 16) & 1u)) >> 16);
}

// ---------------------------------------------------------------------------
// A: per block of 16 points: L1 distances (keys read DIRECTLY from the
// original [hk][f] layout — 16KB/wave working set is L1-resident; r19
// verified that LDS-staging keys is performance-neutral) -> Student-t ->
// per-head normalize -> conv-combine -> softmax -> S_out, then bf16 partial
// pooled -> part (normal cached stores; kernel boundary gives visibility).
// Empirical minimum over 19 structural variants: 22.4us total.
// ---------------------------------------------------------------------------
__global__ __launch_bounds__(256, 2) void mempool_A(
    const float* __restrict__ x, const float* __restrict__ keys,
    const float* __restrict__ conv_w, float* __restrict__ S_out,
    uint32* __restrict__ part) {
  const int t = threadIdx.x;
  const int hkp = t & 63;
  const int q = t >> 6;  // f-quarter 0..3

  __shared__ float4 xl[P1_PTS * 32];      // [p][fq], 8 KB
  __shared__ float accs[P1_PTS][4][128];  // [p][q][hk], 32 KB
  __shared__ float cwsn[P1_PTS][4][32];   // [p][h][k], 8 KB
  __shared__ float sl[P1_PTS][32];        // [p][k], 2 KB

  const int bn0 = blockIdx.x * P1_PTS;

  // Stage x: 512 float4 = 2 per thread, fully coalesced.
  {
    const float4* xg = reinterpret_cast<const float4*>(x) + (size_t)bn0 * 32;
    xl[t] = xg[t];
    xl[t + 256] = xg[t + 256];
  }
  __syncthreads();

  // Key rows hkp and hkp+64, f-quarter q, original layout (L1-resident).
  const float4* kr0 =
      reinterpret_cast<const float4*>(keys + (size_t)hkp * 128 + q * 32);
  const float4* kr1 =
      reinterpret_cast<const float4*>(keys + (size_t)(hkp + 64) * 128 + q * 32);

  float acc0[P1_PTS], acc1[P1_PTS];
#pragma unroll
  for (int p = 0; p < P1_PTS; ++p) acc0[p] = acc1[p] = 0.f;

#pragma unroll
  for (int j = 0; j < 8; ++j) {
    const float4 kv0 = kr0[j];
    const float4 kv1 = kr1[j];
    const int jj = q * 8 + j;
#pragma unroll
    for (int p = 0; p < P1_PTS; ++p) {
      const float4 xv = xl[p * 32 + jj];  // uniform ds_read -> broadcast
      acc0[p] += fabsf(kv0.x - xv.x) + fabsf(kv0.y - xv.y) +
                 fabsf(kv0.z - xv.z) + fabsf(kv0.w - xv.w);
      acc1[p] += fabsf(kv1.x - xv.x) + fabsf(kv1.y - xv.y) +
                 fabsf(kv1.z - xv.z) + fabsf(kv1.w - xv.w);
    }
  }

#pragma unroll
  for (int p = 0; p < P1_PTS; ++p) {
    accs[p][q][hkp] = acc0[p];
    accs[p][q][hkp + 64] = acc1[p];
  }
  __syncthreads();

  // Quarter-combine + Student-t + per-head normalize.
  // 2048 (p,hk) cells / 256 threads = 8 each; 32-lane groups share (p,h).
  const float4 cwv = *reinterpret_cast<const float4*>(conv_w);
  {
    const int hk = t & 127;
    const float cw = (hk & 64) ? ((hk & 32) ? cwv.w : cwv.z)
                               : ((hk & 32) ? cwv.y : cwv.x);
#pragma unroll
    for (int i = 0; i < 8; ++i) {
      const int p = (t >> 7) + 2 * i;
      const float d = accs[p][0][hk] + accs[p][1][hk] + accs[p][2][hk] +
                      accs[p][3][hk];
      const float tv = __builtin_amdgcn_rcpf(1.f + d * d);  // Student-t, tau=1
      float hs = tv;
#pragma unroll
      for (int m = 1; m < 32; m <<= 1) hs += __shfl_xor(hs, m);
      cwsn[p][hk >> 5][hk & 31] = cw * tv * __builtin_amdgcn_rcpf(hs);
    }
  }
  __syncthreads();

  // Conv-combine over heads + softmax over k. 16 p x 32 k = 2 passes.
#pragma unroll
  for (int pp = 0; pp < 2; ++pp) {
    const int p = pp * 8 + (t >> 5);
    const int k = t & 31;
    float sc = cwsn[p][0][k] + cwsn[p][1][k] + cwsn[p][2][k] + cwsn[p][3][k];
    float mx = sc;
#pragma unroll
    for (int m = 1; m < 32; m <<= 1) mx = fmaxf(mx, __shfl_xor(mx, m));
    const float e = __expf(sc - mx);
    float se = e;
#pragma unroll
    for (int m = 1; m < 32; m <<= 1) se += __shfl_xor(se, m);
    const float sv = e * __builtin_amdgcn_rcpf(se);
    S_out[(size_t)(bn0 + p) * 32 + k] = sv;
    sl[p][k] = sv;
  }
  __syncthreads();

  // Partial pooled (bf16 pairs in uint32), normal cached vector stores.
  {
    const int k = t & 31;
    const int fs = t >> 5;
    float4 a0 = {0, 0, 0, 0}, a1 = {0, 0, 0, 0}, a2 = {0, 0, 0, 0},
           a3 = {0, 0, 0, 0};
#pragma unroll
    for (int p = 0; p < P1_PTS; ++p) {
      const float s = sl[p][k];
      const float4 v0 = xl[p * 32 + fs * 4 + 0];
      const float4 v1 = xl[p * 32 + fs * 4 + 1];
      const float4 v2 = xl[p * 32 + fs * 4 + 2];
      const float4 v3 = xl[p * 32 + fs * 4 + 3];
      a0.x += s * v0.x; a0.y += s * v0.y; a0.z += s * v0.z; a0.w += s * v0.w;
      a1.x += s * v1.x; a1.y += s * v1.y; a1.z += s * v1.z; a1.w += s * v1.w;
      a2.x += s * v2.x; a2.y += s * v2.y; a2.z += s * v2.z; a2.w += s * v2.w;
      a3.x += s * v3.x; a3.y += s * v3.y; a3.z += s * v3.z; a3.w += s * v3.w;
    }
    uint32 w0 = f2bf(a0.x) | ((uint32)f2bf(a0.y) << 16);
    uint32 w1 = f2bf(a0.z) | ((uint32)f2bf(a0.w) << 16);
    uint32 w2 = f2bf(a1.x) | ((uint32)f2bf(a1.y) << 16);
    uint32 w3 = f2bf(a1.z) | ((uint32)f2bf(a1.w) << 16);
    uint32 w4 = f2bf(a2.x) | ((uint32)f2bf(a2.y) << 16);
    uint32 w5 = f2bf(a2.z) | ((uint32)f2bf(a2.w) << 16);
    uint32 w6 = f2bf(a3.x) | ((uint32)f2bf(a3.y) << 16);
    uint32 w7 = f2bf(a3.z) | ((uint32)f2bf(a3.w) << 16);
    uint4* dst = reinterpret_cast<uint4*>(
        part + (((size_t)blockIdx.x * 32 + k) * 64 + fs * 8));
    dst[0] = make_uint4(w0, w1, w2, w3);
    dst[1] = make_uint4(w4, w5, w6, w7);
  }
}

// ---------------------------------------------------------------------------
// Out: block = (b,k), 256 threads (r8/r14-proven).
// pooled[f] = sum_{c=0..64} part[b*64+c][k][f] (bf16->f32), then
// out[b][k][fo] = leakyrelu(pooled . lin_w[fo]).
// ---------------------------------------------------------------------------
__global__ __launch_bounds__(256) void mempool_out(
    const uint32* __restrict__ part, const float* __restrict__ lin_w,
    float* __restrict__ out) {
  const int b = blockIdx.x >> 5;
  const int k = blockIdx.x & 31;
  const int t = threadIdx.x;
  const int f2 = t & 63;
  const int ch = t >> 6;  // 0..3

  __shared__ float red[4][128];
  __shared__ float pooled[128];

  float sx = 0.f, sy = 0.f;
  const uint32* pp =
      part + ((size_t)((b * NCHUNK_B + ch * 16) * 32 + k)) * 64 + f2;
#pragma unroll
  for (int cc = 0; cc < 16; ++cc) {
    const uint32 v = pp[(size_t)cc * 32 * 64];
    sx += __uint_as_float(v << 16);
    sy += __uint_as_float(v & 0xFFFF0000u);
  }
  red[ch][f2 * 2] = sx;
  red[ch][f2 * 2 + 1] = sy;
  __syncthreads();

  if (t < 128) pooled[t] = red[0][t] + red[1][t] + red[2][t] + red[3][t];
  __syncthreads();

  if (t < 128) {
    const float4* w4 = reinterpret_cast<const float4*>(lin_w) + t * 32;
    const float4* pl4 = reinterpret_cast<const float4*>(pooled);
    float o = 0.f;
#pragma unroll
    for (int j = 0; j < 32; ++j) {
      const float4 w = w4[j];
      const float4 p = pl4[j];
      o += w.x * p.x + w.y * p.y + w.z * p.z + w.w * p.w;
    }
    o = (o >= 0.f) ? o : 0.01f * o;
    out[(size_t)(b * 32 + k) * 128 + t] = o;
  }
}

// ---------------------------------------------------------------------------
// Fallbacks (no workspace): round-1 structure (known-good).
// ---------------------------------------------------------------------------
__global__ __launch_bounds__(256) void mempool_phase1_fb(
    const float* __restrict__ x, const float* __restrict__ keys,
    const float* __restrict__ conv_w, float* __restrict__ S_out) {
  const int t = threadIdx.x;
  const int hk = t & 127;
  const int half = t >> 7;

  const float4* kq = reinterpret_cast<const float4*>(keys) + hk * 32 + half * 16;
  const float cw = conv_w[(t >> 5) & 3];

  __shared__ float lds_half[128];
  __shared__ float lds_ws[128];

  const int base = blockIdx.x * 8;
  for (int p = 0; p < 8; ++p) {
    const int bn = base + p;
    const float4* xq = reinterpret_cast<const float4*>(x) + bn * 32 + half * 16;
    float a0 = 0.f;
#pragma unroll
    for (int j = 0; j < 16; ++j) {
      const float4 kv = kq[j];
      const float4 xv = xq[j];
      a0 += fabsf(kv.x - xv.x) + fabsf(kv.y - xv.y) + fabsf(kv.z - xv.z) +
            fabsf(kv.w - xv.w);
    }
    if (t >= 128) lds_half[hk] = a0;
    __syncthreads();
    if (t < 128) {
      const float d = a0 + lds_half[hk];
      const float tv = 1.0f / (1.0f + d * d);
      float hs = tv;
#pragma unroll
      for (int m = 1; m < 32; m <<= 1) hs += __shfl_xor(hs, m);
      lds_ws[hk] = cw * tv / hs;
    }
    __syncthreads();
    if (t < 32) {
      float sc = lds_ws[t] + lds_ws[32 + t] + lds_ws[64 + t] + lds_ws[96 + t];
      float mx = sc;
#pragma unroll
      for (int m = 1; m < 32; m <<= 1) mx = fmaxf(mx, __shfl_xor(mx, m));
      const float e = __expf(sc - mx);
      float se = e;
#pragma unroll
      for (int m = 1; m < 32; m <<= 1) se += __shfl_xor(se, m);
      S_out[bn * 32 + t] = e / se;
    }
    __syncthreads();
  }
}

__global__ __launch_bounds__(256) void mempool_phase2_fb(
    const float* __restrict__ x, const float* __restrict__ S,
    const float* __restrict__ lin_w, float* __restrict__ out) {
  const int b = blockIdx.x >> 5;
  const int k = blockIdx.x & 31;
  const int t = threadIdx.x;
  const int fq = t & 31;
  const int seg = t >> 5;

  const float4* xq = reinterpret_cast<const float4*>(x) + (size_t)b * 1024 * 32;
  const float* Sb = S + (size_t)b * 1024 * 32 + k;

  float4 acc = {0.f, 0.f, 0.f, 0.f};
  const int n0 = seg * 128;
#pragma unroll 4
  for (int n = n0; n < n0 + 128; ++n) {
    const float sv = Sb[(size_t)n * 32];
    const float4 xv = xq[n * 32 + fq];
    acc.x += sv * xv.x;
    acc.y += sv * xv.y;
    acc.z += sv * xv.z;
    acc.w += sv * xv.w;
  }

  __shared__ float4 red[8][32];
  red[seg][fq] = acc;
  __syncthreads();

  __shared__ float4 pooled4[32];
  if (t < 32) {
    float4 a = red[0][t];
#pragma unroll
    for (int ss = 1; ss < 8; ++ss) {
      const float4 r = red[ss][t];
      a.x += r.x; a.y += r.y; a.z += r.z; a.w += r.w;
    }
    pooled4[t] = a;
  }
  __syncthreads();

  if (t < 128) {
    const float4* wq = reinterpret_cast<const float4*>(lin_w) + t * 32;
    float o = 0.f;
#pragma unroll
    for (int j = 0; j < 32; ++j) {
      const float4 w = wq[j];
      const float4 p = pooled4[j];
      o += w.x * p.x + w.y * p.y + w.z * p.z + w.w * p.w;
    }
    o = (o >= 0.f) ? o : 0.01f * o;
    out[(size_t)(b * 32 + k) * 128 + t] = o;
  }
}

extern "C" void kernel_launch(void* const* d_in, const int* in_sizes, int n_in,
                              void* d_out, int out_size, void* d_ws, size_t ws_size,
                              hipStream_t stream) {
  const float* x = (const float*)d_in[0];       // [8,1024,128]
  const float* keys = (const float*)d_in[1];    // [4,32,128]
  const float* conv_w = (const float*)d_in[2];  // [4]
  const float* lin_w = (const float*)d_in[3];   // [128,128]

  float* out = (float*)d_out;            // [8,32,128]
  float* S_out = (float*)d_out + 32768;  // [8,1024,32]

  const size_t part_bytes = (size_t)P1_BLOCKS * 32 * 128 * 2;  // 4 MB bf16

  if (ws_size >= part_bytes) {
    uint32* part = (uint32*)d_ws;
    mempool_A<<<P1_BLOCKS, 256, 0, stream>>>(x, keys, conv_w, S_out, part);
    mempool_out<<<8 * 32, 256, 0, stream>>>(part, lin_w, out);
  } else {
    mempool_phase1_fb<<<1024, 256, 0, stream>>>(x, keys, conv_w, S_out);
    mempool_phase2_fb<<<8 * 32, 256, 0, stream>>>(x, S_out, lin_w, out);
  }
}